// Round 10
// baseline (172.717 us; speedup 1.0000x reference)
//
#include <hip/hip_runtime.h>
#include <hip/hip_bf16.h>

#define B_ 1024
#define P_ 8
#define D_ 2048
#define FD_ (P_ * D_)   // 16384
#define NID 64
#define MARGIN_ 0.3f
#define EPS_ 1e-12f

typedef unsigned short u16;
typedef float float4_t __attribute__((ext_vector_type(4)));

#define AS1 __attribute__((address_space(1)))
#define AS3 __attribute__((address_space(3)))

__device__ __forceinline__ float bf2f(u16 v) {
    unsigned x = (unsigned)v << 16;
    float f;
    __builtin_memcpy(&f, &x, 4);
    return f;
}

// ---------------- workspace layout (bytes) ----------------
static const size_t OFF_COUNTS = 0;         // 64 fp32
static const size_t OFF_OFFS   = 256;       // 64 int
static const size_t OFF_PERM   = 512;       // 1024 int -> ends 4608
static const size_t OFF_NEG    = 4608;      // 1 fp32
static const size_t OFF_DONE   = 4616;      // 1 int (k_lossred done counter)
static const size_t OFF_POS    = 8176;      // 1 fp32
static const size_t OFF_S      = 8192;      // 1024*8 fp32 = 32 KB -> 40960
static const size_t OFF_SQ     = 40960;     // 1024*8 fp32 = 32 KB -> 73728
static const size_t OFF_DAP    = 73728;     // 1024 fp32 -> 77824
static const size_t OFF_FB     = 131072;    // 1024*16384 fp8 = 16 MB
static const size_t OFF_PD     = OFF_FB + (size_t)B_ * FD_;  // 8 planes * 1024*1024 bf16 = 16 MB
// total ~33.7 MB

// ---------------- kernel 1: fused prep ----------------
// blocks 0..1023: fp8 cast + per-plane sq (linear fb layout)
// block 1024:     label histogram + prefix + perm + negcnt + zero S/possum/done
__global__ void k_prep(const float* __restrict__ feats, const int* __restrict__ labels,
                       unsigned char* __restrict__ fb, float* __restrict__ sq,
                       float* countsf, int* offs, int* perm, float* negcnt,
                       float* S, float* possum, int* done) {
    int tid = threadIdx.x;
    if (blockIdx.x < B_) {
        int i = blockIdx.x;
        int w = tid >> 6, lane = tid & 63;
        const float* frow = feats + (size_t)i * FD_;
        unsigned char* brow = fb + (size_t)i * FD_;
#pragma unroll
        for (int pp = 0; pp < 2; pp++) {
            int p = w * 2 + pp;
            int off = p * D_;
            float s2 = 0.f;
#pragma unroll
            for (int ch = 0; ch < 8; ch++) {
                int d = off + ch * 256 + lane * 4;
                float4 f = *(const float4*)(frow + d);
                int pk = __builtin_amdgcn_cvt_pk_fp8_f32(f.x, f.y, 0, false);
                pk = __builtin_amdgcn_cvt_pk_fp8_f32(f.z, f.w, pk, true);
                *(unsigned int*)(brow + d) = (unsigned int)pk;
                s2 += f.x * f.x + f.y * f.y + f.z * f.z + f.w * f.w;
            }
            for (int o = 32; o; o >>= 1) s2 += __shfl_down(s2, o, 64);
            if (lane == 0) sq[i * P_ + p] = s2;
        }
        return;
    }
    // ---- block 1024: counts + zeroing ----
    __shared__ int h[NID], o[NID], cur[NID];
    if (tid < NID) h[tid] = 0;
    __syncthreads();
    for (int i = tid; i < B_; i += 256) atomicAdd(&h[labels[i]], 1);
    __syncthreads();
    if (tid == 0) {
        int acc = 0;
        long long ss = 0;
        for (int c = 0; c < NID; c++) {
            o[c] = acc;
            acc += h[c];
            ss += (long long)h[c] * h[c];
        }
        *negcnt = (float)((long long)B_ * B_ - ss);
        *possum = 0.f;
        done[0] = 0;
    }
    __syncthreads();
    if (tid < NID) {
        countsf[tid] = (float)h[tid];
        offs[tid] = o[tid];
        cur[tid] = o[tid];
    }
    __syncthreads();
    for (int i = tid; i < B_; i += 256) {
        int pos = atomicAdd(&cur[labels[i]], 1);
        perm[pos] = i;
    }
    for (int i = tid; i < B_ * P_; i += 256) S[i] = 0.f;
}

// ---------------- kernel 2: fp8 MFMA pair kernel, 8-wave strips, 2-phase dbuf --------
// Linear grid 512: plane p = bid & 7 (block-id round-robins across the 8 XCDs ->
// each XCD owns ONE plane; its 2 MB fb slice L2-fits -> staging is L2-hit, proven
// R9: FETCH 66 -> 8.5 MB). Spatial t = bid>>3 -> 128x128 (i,j) tile.
// 512 threads = 8 waves; wave w owns the 32x64 strip (wr=w>>1 row-slice, wc=w&1
// col-half) for the FULL K=2048: no accumulator exchange (R3-safe), ALL 8 waves run
// the epilogue (32 outputs/lane vs R0's 64 on half the waves). LDS 67.5 KB ->
// 2 blocks/CU = 16 waves/CU = 4 waves/SIMD (the only lever that measurably moved
// this kernel: R0@16w/CU=42.2 vs R8/R9@8w/CU=43-46). Per wave per K-step: 32 MFMA,
// 6 ds_read_b64, 4 global_load_lds — 4 independent feeders per SIMD matrix pipe.
// K-loop: 2-phase double-buffer (STAGE(next) before COMPUTE(cur), one sync/step).
// Staging keeps the validated 128-B window geometry: phys 16-B chunk =
// logical ^ (row&7) via pre-swizzled global source, linear global_load_lds dest.
__global__ __launch_bounds__(512, 4) void k_pairs(const unsigned char* __restrict__ fb,
                                                  const float* __restrict__ sq,
                                                  const int* __restrict__ labels,
                                                  float* __restrict__ S,
                                                  u16* __restrict__ pd) {
    const int bid = blockIdx.x;
    const int p = bid & 7;            // plane == XCD (bijective, 512 % 8 == 0)
    const int t = bid >> 3;           // 0..63 spatial
    const int i0 = (t >> 3) * 128, j0 = (t & 7) * 128;

    __shared__ __align__(16) unsigned char smem[65536];  // buf q: As q*32K, Bs q*32K+16K
    __shared__ float sqAs[128], sqBs[128];
    __shared__ int labA[128], labB[128];
    const int tid = threadIdx.x;
    const int lane = tid & 63, w = tid >> 6;   // w 0..7
    const int wr = w >> 1, wc = w & 1;         // 32-row slice, 64-col half
    if (tid < 128) {
        sqAs[tid] = sq[(i0 + tid) * 8 + p];
        labA[tid] = labels[i0 + tid];
    } else if (tid < 256) {
        int u = tid - 128;
        sqBs[u] = sq[(j0 + u) * 8 + p];
        labB[u] = labels[j0 + u];
    }

    const int lhi = lane >> 4, llo = lane & 15;
    const int sl = llo & 7;
    const int lr = lane >> 3;
    const int lc = (lane & 7) ^ lr;

    const size_t colbase = (size_t)p * D_ + (size_t)lc * 16;
    const unsigned char* gA[2];
    const unsigned char* gB[2];
    unsigned char* lA[2];
    unsigned char* lB[2];
#pragma unroll
    for (int inst = 0; inst < 2; inst++) {
        int r0 = w * 16 + inst * 8;   // 8 waves x 2 insts x 8 rows = 128 rows of A and B
        gA[inst] = fb + (size_t)(i0 + r0 + lr) * FD_ + colbase;
        gB[inst] = fb + (size_t)(j0 + r0 + lr) * FD_ + colbase;
        lA[inst] = smem + r0 * 128;           // As base; + BUF*32768
        lB[inst] = smem + 16384 + r0 * 128;   // Bs base; + BUF*32768
    }

    float4_t acc[2][4];
#pragma unroll
    for (int a = 0; a < 2; a++)
#pragma unroll
        for (int b = 0; b < 4; b++) acc[a][b] = (float4_t){0.f, 0.f, 0.f, 0.f};

#define STAGE(BUF, KB)                                                                    \
    {                                                                                     \
        const int koff_ = (KB) * 128;                                                     \
        _Pragma("unroll") for (int inst = 0; inst < 2; inst++) {                          \
            __builtin_amdgcn_global_load_lds((const AS1 void*)(gA[inst] + koff_),         \
                                             (AS3 void*)(lA[inst] + (BUF) * 32768),       \
                                             16, 0, 0);                                   \
            __builtin_amdgcn_global_load_lds((const AS1 void*)(gB[inst] + koff_),         \
                                             (AS3 void*)(lB[inst] + (BUF) * 32768),       \
                                             16, 0, 0);                                   \
        }                                                                                 \
    }

#define COMPUTE(BUF)                                                                      \
    {                                                                                     \
        _Pragma("unroll") for (int ks = 0; ks < 4; ks++) {                                \
            const int pcb = ((2 * ks + (lhi >> 1)) ^ sl) * 16 + (lhi & 1) * 8;            \
            long af[2], bf[4];                                                            \
            _Pragma("unroll") for (int a = 0; a < 2; a++)                                 \
                af[a] = *(const long*)(smem + (BUF) * 32768 +                             \
                                       (wr * 32 + a * 16 + llo) * 128 + pcb);             \
            _Pragma("unroll") for (int b = 0; b < 4; b++)                                 \
                bf[b] = *(const long*)(smem + (BUF) * 32768 + 16384 +                     \
                                       (wc * 64 + b * 16 + llo) * 128 + pcb);             \
            _Pragma("unroll") for (int a = 0; a < 2; a++)                                 \
                _Pragma("unroll") for (int b = 0; b < 4; b++)                             \
                    acc[a][b] = __builtin_amdgcn_mfma_f32_16x16x32_fp8_fp8(               \
                        af[a], bf[b], acc[a][b], 0, 0, 0);                                \
        }                                                                                 \
    }

    STAGE(0, 0);
    __syncthreads();  // buf0 ready (also publishes sq/lab LDS arrays)
#pragma unroll 1
    for (int kb2 = 0; kb2 < 7; kb2++) {
        STAGE(1, 2 * kb2 + 1);   // prefetch next step under this step's MFMAs
        COMPUTE(0);              // step 2*kb2
        __syncthreads();         // drain buf1 loads (covered) + WAR gate for buf0
        STAGE(0, 2 * kb2 + 2);
        COMPUTE(1);              // step 2*kb2+1
        __syncthreads();
    }
    STAGE(1, 15);
    COMPUTE(0);                  // step 14
    __syncthreads();
    COMPUTE(1);                  // step 15

#undef STAGE
#undef COMPUTE

    // ---- epilogue: every wave finishes its own 32x64 strip (no exchange) ----
    u16* outp = pd + (size_t)p * B_ * B_;
    float rs[2][4];
#pragma unroll
    for (int a = 0; a < 2; a++)
#pragma unroll
        for (int r = 0; r < 4; r++) rs[a][r] = 0.f;
#pragma unroll
    for (int a = 0; a < 2; a++) {
        int la0 = labA[wr * 32 + a * 16 + lhi * 4 + 0];
        int la1 = labA[wr * 32 + a * 16 + lhi * 4 + 1];
        int la2 = labA[wr * 32 + a * 16 + lhi * 4 + 2];
        int la3 = labA[wr * 32 + a * 16 + lhi * 4 + 3];
#pragma unroll
        for (int b = 0; b < 4; b++) {
            int jl = wc * 64 + b * 16 + llo;
            int lb = labB[jl];
#pragma unroll
            for (int r = 0; r < 4; r++) {
                int il = wr * 32 + a * 16 + lhi * 4 + r;
                float tt = acc[a][b][r];
                float d2 = sqAs[il] + sqBs[jl] - 2.0f * tt;
                outp[(size_t)(i0 + il) * B_ + (j0 + jl)] =
                    __bfloat16_as_ushort(__float2bfloat16(sqrtf(fmaxf(d2, EPS_))));
                int la = (r == 0) ? la0 : (r == 1) ? la1 : (r == 2) ? la2 : la3;
                if (lb == la) rs[a][r] += tt;
            }
        }
    }
#pragma unroll
    for (int a = 0; a < 2; a++)
#pragma unroll
        for (int r = 0; r < 4; r++) {
            float v = rs[a][r];
            v += __shfl_xor(v, 1, 64);
            v += __shfl_xor(v, 2, 64);
            v += __shfl_xor(v, 4, 64);
            v += __shfl_xor(v, 8, 64);
            if (llo == 0)
                atomicAdd(&S[(size_t)(i0 + wr * 32 + a * 16 + lhi * 4 + r) * 8 + p], v);
        }
}

// ---------------- kernel 3: d_ap from Gram row sums ----------------
// grid 64 (one class), block 64
__global__ void k_dap(const float* __restrict__ S, const float* __restrict__ sq,
                      const float* __restrict__ countsf, const int* __restrict__ offs,
                      const int* __restrict__ perm, float* __restrict__ dap) {
    int c = blockIdx.x;
    int tid = threadIdx.x;
    int cnt = (int)countsf[c];
    int off = offs[c];
    __shared__ float T[8];
    if (tid < 8) {
        float t = 0.f;
        for (int m = 0; m < cnt; m++) t += S[(size_t)perm[off + m] * 8 + tid];
        T[tid] = t;
    }
    __syncthreads();
    float n = fmaxf((float)cnt, 1.f);
    float inv = 1.f / n, inv2 = inv * inv;
    for (int m = tid; m < cnt; m += 64) {
        int i = perm[off + m];
        float d = 0.f;
#pragma unroll
        for (int p = 0; p < 8; p++) {
            float d2 = sq[i * 8 + p] - 2.f * inv * S[(size_t)i * 8 + p] + inv2 * T[p];
            d += sqrtf(fmaxf(d2, EPS_));
        }
        dap[i] = d;
    }
}

// ---------------- kernel 4: masked margin reduction + fused finalize ----------------
// vectorized: each thread owns 4 consecutive j (ushort4 pd loads, 8 B/lane).
// LAST block (device done-counter) writes out = possum/negcnt.
__global__ void k_lossred(const u16* __restrict__ pd, const float* __restrict__ dap,
                          const int* __restrict__ labels, float* possum,
                          const float* __restrict__ negcnt, int* __restrict__ done,
                          float* __restrict__ out) {
    int i = blockIdx.x;
    int tid = threadIdx.x;  // 256
    float di = dap[i];
    int li = labels[i];
    int j0 = tid * 4;
    float d0 = 0.f, d1 = 0.f, d2 = 0.f, d3 = 0.f;
#pragma unroll
    for (int p = 0; p < P_; p++) {
        ushort4 v = *(const ushort4*)&pd[(size_t)p * B_ * B_ + (size_t)i * B_ + j0];
        d0 += bf2f(v.x);
        d1 += bf2f(v.y);
        d2 += bf2f(v.z);
        d3 += bf2f(v.w);
    }
    int4 lj = *(const int4*)&labels[j0];
    float4 dj = *(const float4*)&dap[j0];
    float lsum = 0.f;
    if (lj.x != li) lsum += fmaxf(di + dj.x - d0 + MARGIN_, 0.f);
    if (lj.y != li) lsum += fmaxf(di + dj.y - d1 + MARGIN_, 0.f);
    if (lj.z != li) lsum += fmaxf(di + dj.z - d2 + MARGIN_, 0.f);
    if (lj.w != li) lsum += fmaxf(di + dj.w - d3 + MARGIN_, 0.f);
    for (int o = 32; o; o >>= 1) lsum += __shfl_down(lsum, o, 64);
    __shared__ float red[4];
    int wid = tid >> 6, lane = tid & 63;
    if (lane == 0) red[wid] = lsum;
    __syncthreads();
    if (tid == 0) {
        atomicAdd(possum, red[0] + red[1] + red[2] + red[3]);
        __threadfence();
        int v = atomicAdd(done, 1);
        if (v == B_ - 1) {
            float ps = atomicAdd(possum, 0.f);  // coherent read after all adds
            out[0] = ps / negcnt[0];
        }
    }
}

// ---------------- launch: 4 nodes ----------------
extern "C" void kernel_launch(void* const* d_in, const int* in_sizes, int n_in,
                              void* d_out, int out_size, void* d_ws, size_t ws_size,
                              hipStream_t stream) {
    const float* feats = (const float*)d_in[0];
    const int* labels  = (const int*)d_in[1];
    float* out = (float*)d_out;

    char* w = (char*)d_ws;
    float* countsf = (float*)(w + OFF_COUNTS);
    int* offs      = (int*)(w + OFF_OFFS);
    int* perm      = (int*)(w + OFF_PERM);
    float* negcnt  = (float*)(w + OFF_NEG);
    int* done      = (int*)(w + OFF_DONE);
    float* possum  = (float*)(w + OFF_POS);
    float* S       = (float*)(w + OFF_S);
    float* sq      = (float*)(w + OFF_SQ);
    float* dap     = (float*)(w + OFF_DAP);
    unsigned char* fb = (unsigned char*)(w + OFF_FB);
    u16* pd        = (u16*)(w + OFF_PD);

    k_prep<<<B_ + 1, 256, 0, stream>>>(feats, labels, fb, sq, countsf, offs, perm,
                                       negcnt, S, possum, done);
    k_pairs<<<512, 512, 0, stream>>>(fb, sq, labels, S, pd);
    k_dap<<<NID, 64, 0, stream>>>(S, sq, countsf, offs, perm, dap);
    k_lossred<<<B_, 256, 0, stream>>>(pd, dap, labels, possum, negcnt, done, out);
}

// Round 11
// 166.160 us; speedup vs baseline: 1.0395x; 1.0395x over previous
//
#include <hip/hip_runtime.h>
#include <hip/hip_bf16.h>

#define B_ 1024
#define P_ 8
#define D_ 2048
#define FD_ (P_ * D_)   // 16384
#define NID 64
#define MARGIN_ 0.3f
#define EPS_ 1e-12f

typedef unsigned short u16;
typedef float float4_t __attribute__((ext_vector_type(4)));

#define AS1 __attribute__((address_space(1)))
#define AS3 __attribute__((address_space(3)))

__device__ __forceinline__ float bf2f(u16 v) {
    unsigned x = (unsigned)v << 16;
    float f;
    __builtin_memcpy(&f, &x, 4);
    return f;
}

// ---------------- workspace layout (bytes) ----------------
static const size_t OFF_COUNTS = 0;         // 64 fp32
static const size_t OFF_OFFS   = 256;       // 64 int
static const size_t OFF_PERM   = 512;       // 1024 int -> ends 4608
static const size_t OFF_NEG    = 4608;      // 1 fp32
static const size_t OFF_DONE   = 4616;      // 1 int (k_lossred done counter)
static const size_t OFF_POS    = 8176;      // 1 fp32
static const size_t OFF_S      = 8192;      // 1024*8 fp32 = 32 KB -> 40960
static const size_t OFF_SQ     = 40960;     // 1024*8 fp32 = 32 KB -> 73728
static const size_t OFF_DAP    = 73728;     // 1024 fp32 -> 77824
static const size_t OFF_FB     = 131072;    // 1024*16384 fp8 = 16 MB
static const size_t OFF_PD     = OFF_FB + (size_t)B_ * FD_;  // 8 planes * 1024*1024 bf16 = 16 MB
// total ~33.7 MB

// ---------------- kernel 1: fused prep ----------------
// blocks 0..1023: fp8 cast + per-plane sq (linear fb layout)
// block 1024:     label histogram + prefix + perm + negcnt + zero S/possum/done
__global__ void k_prep(const float* __restrict__ feats, const int* __restrict__ labels,
                       unsigned char* __restrict__ fb, float* __restrict__ sq,
                       float* countsf, int* offs, int* perm, float* negcnt,
                       float* S, float* possum, int* done) {
    int tid = threadIdx.x;
    if (blockIdx.x < B_) {
        int i = blockIdx.x;
        int w = tid >> 6, lane = tid & 63;
        const float* frow = feats + (size_t)i * FD_;
        unsigned char* brow = fb + (size_t)i * FD_;
#pragma unroll
        for (int pp = 0; pp < 2; pp++) {
            int p = w * 2 + pp;
            int off = p * D_;
            float s2 = 0.f;
#pragma unroll
            for (int ch = 0; ch < 8; ch++) {
                int d = off + ch * 256 + lane * 4;
                float4 f = *(const float4*)(frow + d);
                int pk = __builtin_amdgcn_cvt_pk_fp8_f32(f.x, f.y, 0, false);
                pk = __builtin_amdgcn_cvt_pk_fp8_f32(f.z, f.w, pk, true);
                *(unsigned int*)(brow + d) = (unsigned int)pk;
                s2 += f.x * f.x + f.y * f.y + f.z * f.z + f.w * f.w;
            }
            for (int o = 32; o; o >>= 1) s2 += __shfl_down(s2, o, 64);
            if (lane == 0) sq[i * P_ + p] = s2;
        }
        return;
    }
    // ---- block 1024: counts + zeroing ----
    __shared__ int h[NID], o[NID], cur[NID];
    if (tid < NID) h[tid] = 0;
    __syncthreads();
    for (int i = tid; i < B_; i += 256) atomicAdd(&h[labels[i]], 1);
    __syncthreads();
    if (tid == 0) {
        int acc = 0;
        long long ss = 0;
        for (int c = 0; c < NID; c++) {
            o[c] = acc;
            acc += h[c];
            ss += (long long)h[c] * h[c];
        }
        *negcnt = (float)((long long)B_ * B_ - ss);
        *possum = 0.f;
        done[0] = 0;
    }
    __syncthreads();
    if (tid < NID) {
        countsf[tid] = (float)h[tid];
        offs[tid] = o[tid];
        cur[tid] = o[tid];
    }
    __syncthreads();
    for (int i = tid; i < B_; i += 256) {
        int pos = atomicAdd(&cur[labels[i]], 1);
        perm[pos] = i;
    }
    for (int i = tid; i < B_ * P_; i += 256) S[i] = 0.f;
}

// ---------------- kernel 2: fp8 MFMA pair kernel (round-0 geometry, verbatim) --------
// grid (8,8,8): 128x128 (i,j) tile, z = plane p. block 512 = 4 spatial x 2 K-half waves.
// K window per iter = 128 B (fp8), 8 iters per half. XOR chunk swizzle (16-B chunks,
// physical = logical ^ (row&7)). Frags: ds_read_b64, 4 K-steps of 32, 64 MFMA per
// barrier pair (the density constraint: structures with <64 MFMA/wave/step all lost —
// R5/R6/R10). Epilogue: h1 stores acc to LDS (then dead), h0 combines + sqrt -> pd,
// masked row sums -> S. DO NOT restructure the epilogue: making acc live in both
// h-branches past the barrier spills the accumulators to scratch (R3: VGPR 64->60,
// WRITE_SIZE 21.5 MB -> 611 MB, 3x slowdown). DO NOT narrow staging windows below
// 128 B/row (R1: partial-line traffic, WRITE +16 MB). Measured 42.2 us = 34% of the
// fp8 MFMA ceiling = the documented 2-phase-structure ceiling; dbuf/prefetch (R9),
// XCD-plane L2 affinity (R9, FETCH 66->8.5 MB), occupancy 2-16 waves/CU (R7-R10)
// were all time-neutral or worse on this structure.
__global__ __launch_bounds__(512, 4) void k_pairs(const unsigned char* __restrict__ fb,
                                                  const float* __restrict__ sq,
                                                  const int* __restrict__ labels,
                                                  float* __restrict__ S,
                                                  u16* __restrict__ pd) {
    const int i0 = blockIdx.y * 128, j0 = blockIdx.x * 128;
    const int p = blockIdx.z;
    __shared__ __align__(16) unsigned char smem[65536];  // As[h]:[h*16K), Bs[h]:[32K+h*16K)
    __shared__ float sqAs[128], sqBs[128];
    __shared__ int labA[128], labB[128];
    const int tid = threadIdx.x;
    const int lane = tid & 63, wid = tid >> 6;
    const int s = wid & 3, h = wid >> 2;
    if (tid < 128) {
        sqAs[tid] = sq[(i0 + tid) * 8 + p];
        labA[tid] = labels[i0 + tid];
    } else if (tid < 256) {
        int t = tid - 128;
        sqBs[t] = sq[(j0 + t) * 8 + p];
        labB[t] = labels[j0 + t];
    }

    const int wi = (s >> 1) * 64, wj = (s & 1) * 64;
    const int lhi = lane >> 4, llo = lane & 15;
    const int sl = llo & 7;
    const int lr = lane >> 3;
    const int lc = (lane & 7) ^ lr;

    unsigned char* const As = smem + h * 16384;
    unsigned char* const Bs = smem + 32768 + h * 16384;

    const size_t colbase = (size_t)p * D_ + (size_t)h * 1024 + (size_t)lc * 16;
    const unsigned char* gA[4];
    const unsigned char* gB[4];
    unsigned char* lA[4];
    unsigned char* lB[4];
#pragma unroll
    for (int inst = 0; inst < 4; inst++) {
        int r0 = s * 32 + inst * 8;
        gA[inst] = fb + (size_t)(i0 + r0 + lr) * FD_ + colbase;
        gB[inst] = fb + (size_t)(j0 + r0 + lr) * FD_ + colbase;
        lA[inst] = As + r0 * 128;  // wave-uniform base; HW adds lane*16B
        lB[inst] = Bs + r0 * 128;
    }

    float4_t acc[4][4];
#pragma unroll
    for (int a = 0; a < 4; a++)
#pragma unroll
        for (int b = 0; b < 4; b++) acc[a][b] = (float4_t){0.f, 0.f, 0.f, 0.f};

    for (int kb = 0; kb < 8; kb++) {
        const int koff = kb * 128;
        __syncthreads();
#pragma unroll
        for (int inst = 0; inst < 4; inst++) {
            __builtin_amdgcn_global_load_lds((const AS1 void*)(gA[inst] + koff),
                                             (AS3 void*)lA[inst], 16, 0, 0);
            __builtin_amdgcn_global_load_lds((const AS1 void*)(gB[inst] + koff),
                                             (AS3 void*)lB[inst], 16, 0, 0);
        }
        __syncthreads();
#pragma unroll
        for (int ks = 0; ks < 4; ks++) {
            // lane quad lhi needs bytes [ks*32 + lhi*8, +8): logical chunk 2ks+(lhi>>1),
            // sub-offset (lhi&1)*8; physical chunk = logical ^ (row&7)
            const int pcb = ((2 * ks + (lhi >> 1)) ^ sl) * 16 + (lhi & 1) * 8;
            long af[4], bf[4];
#pragma unroll
            for (int a = 0; a < 4; a++) {
                af[a] = *(const long*)(As + (wi + a * 16 + llo) * 128 + pcb);
                bf[a] = *(const long*)(Bs + (wj + a * 16 + llo) * 128 + pcb);
            }
#pragma unroll
            for (int a = 0; a < 4; a++)
#pragma unroll
                for (int b = 0; b < 4; b++)
                    acc[a][b] = __builtin_amdgcn_mfma_f32_16x16x32_fp8_fp8(
                        af[a], bf[b], acc[a][b], 0, 0, 0);
        }
    }
    // ---- epilogue: combine K-halves, sqrt -> pd, masked row sums -> S ----
    __syncthreads();  // all ds_reads of smem done before reuse
    float* ep = (float*)smem;
    if (h == 1) {
#pragma unroll
        for (int a = 0; a < 4; a++)
#pragma unroll
            for (int b = 0; b < 4; b++)
                *(float4_t*)&ep[(((s * 4 + a) * 4 + b) * 64 + lane) * 4] = acc[a][b];
    }
    __syncthreads();
    if (h == 0) {
        u16* outp = pd + (size_t)p * B_ * B_;
        float rs[4][4];
#pragma unroll
        for (int a = 0; a < 4; a++)
#pragma unroll
            for (int r = 0; r < 4; r++) rs[a][r] = 0.f;
#pragma unroll
        for (int a = 0; a < 4; a++) {
            int la0 = labA[wi + a * 16 + lhi * 4 + 0];
            int la1 = labA[wi + a * 16 + lhi * 4 + 1];
            int la2 = labA[wi + a * 16 + lhi * 4 + 2];
            int la3 = labA[wi + a * 16 + lhi * 4 + 3];
#pragma unroll
            for (int b = 0; b < 4; b++) {
                float4_t o = *(const float4_t*)&ep[(((s * 4 + a) * 4 + b) * 64 + lane) * 4];
                int lb = labB[wj + b * 16 + llo];
                int jl = wj + b * 16 + llo;
#pragma unroll
                for (int r = 0; r < 4; r++) {
                    int il = wi + a * 16 + lhi * 4 + r;
                    float t = acc[a][b][r] + o[r];
                    float d2 = sqAs[il] + sqBs[jl] - 2.0f * t;
                    outp[(size_t)(i0 + il) * B_ + (j0 + jl)] =
                        __bfloat16_as_ushort(__float2bfloat16(sqrtf(fmaxf(d2, EPS_))));
                    int la = (r == 0) ? la0 : (r == 1) ? la1 : (r == 2) ? la2 : la3;
                    if (lb == la) rs[a][r] += t;
                }
            }
        }
#pragma unroll
        for (int a = 0; a < 4; a++)
#pragma unroll
            for (int r = 0; r < 4; r++) {
                float v = rs[a][r];
                v += __shfl_xor(v, 1, 64);
                v += __shfl_xor(v, 2, 64);
                v += __shfl_xor(v, 4, 64);
                v += __shfl_xor(v, 8, 64);
                if (llo == 0)
                    atomicAdd(&S[(size_t)(i0 + wi + a * 16 + lhi * 4 + r) * 8 + p], v);
            }
    }
}

// ---------------- kernel 3: d_ap from Gram row sums ----------------
// grid 64 (one class), block 64
__global__ void k_dap(const float* __restrict__ S, const float* __restrict__ sq,
                      const float* __restrict__ countsf, const int* __restrict__ offs,
                      const int* __restrict__ perm, float* __restrict__ dap) {
    int c = blockIdx.x;
    int tid = threadIdx.x;
    int cnt = (int)countsf[c];
    int off = offs[c];
    __shared__ float T[8];
    if (tid < 8) {
        float t = 0.f;
        for (int m = 0; m < cnt; m++) t += S[(size_t)perm[off + m] * 8 + tid];
        T[tid] = t;
    }
    __syncthreads();
    float n = fmaxf((float)cnt, 1.f);
    float inv = 1.f / n, inv2 = inv * inv;
    for (int m = tid; m < cnt; m += 64) {
        int i = perm[off + m];
        float d = 0.f;
#pragma unroll
        for (int p = 0; p < 8; p++) {
            float d2 = sq[i * 8 + p] - 2.f * inv * S[(size_t)i * 8 + p] + inv2 * T[p];
            d += sqrtf(fmaxf(d2, EPS_));
        }
        dap[i] = d;
    }
}

// ---------------- kernel 4: masked margin reduction + fused finalize ----------------
// vectorized: each thread owns 4 consecutive j (ushort4 pd loads, 8 B/lane).
// LAST block (device done-counter) writes out = possum/negcnt.
__global__ void k_lossred(const u16* __restrict__ pd, const float* __restrict__ dap,
                          const int* __restrict__ labels, float* possum,
                          const float* __restrict__ negcnt, int* __restrict__ done,
                          float* __restrict__ out) {
    int i = blockIdx.x;
    int tid = threadIdx.x;  // 256
    float di = dap[i];
    int li = labels[i];
    int j0 = tid * 4;
    float d0 = 0.f, d1 = 0.f, d2 = 0.f, d3 = 0.f;
#pragma unroll
    for (int p = 0; p < P_; p++) {
        ushort4 v = *(const ushort4*)&pd[(size_t)p * B_ * B_ + (size_t)i * B_ + j0];
        d0 += bf2f(v.x);
        d1 += bf2f(v.y);
        d2 += bf2f(v.z);
        d3 += bf2f(v.w);
    }
    int4 lj = *(const int4*)&labels[j0];
    float4 dj = *(const float4*)&dap[j0];
    float lsum = 0.f;
    if (lj.x != li) lsum += fmaxf(di + dj.x - d0 + MARGIN_, 0.f);
    if (lj.y != li) lsum += fmaxf(di + dj.y - d1 + MARGIN_, 0.f);
    if (lj.z != li) lsum += fmaxf(di + dj.z - d2 + MARGIN_, 0.f);
    if (lj.w != li) lsum += fmaxf(di + dj.w - d3 + MARGIN_, 0.f);
    for (int o = 32; o; o >>= 1) lsum += __shfl_down(lsum, o, 64);
    __shared__ float red[4];
    int wid = tid >> 6, lane = tid & 63;
    if (lane == 0) red[wid] = lsum;
    __syncthreads();
    if (tid == 0) {
        atomicAdd(possum, red[0] + red[1] + red[2] + red[3]);
        __threadfence();
        int v = atomicAdd(done, 1);
        if (v == B_ - 1) {
            float ps = atomicAdd(possum, 0.f);  // coherent read after all adds
            out[0] = ps / negcnt[0];
        }
    }
}

// ---------------- launch: 4 nodes ----------------
extern "C" void kernel_launch(void* const* d_in, const int* in_sizes, int n_in,
                              void* d_out, int out_size, void* d_ws, size_t ws_size,
                              hipStream_t stream) {
    const float* feats = (const float*)d_in[0];
    const int* labels  = (const int*)d_in[1];
    float* out = (float*)d_out;

    char* w = (char*)d_ws;
    float* countsf = (float*)(w + OFF_COUNTS);
    int* offs      = (int*)(w + OFF_OFFS);
    int* perm      = (int*)(w + OFF_PERM);
    float* negcnt  = (float*)(w + OFF_NEG);
    int* done      = (int*)(w + OFF_DONE);
    float* possum  = (float*)(w + OFF_POS);
    float* S       = (float*)(w + OFF_S);
    float* sq      = (float*)(w + OFF_SQ);
    float* dap     = (float*)(w + OFF_DAP);
    unsigned char* fb = (unsigned char*)(w + OFF_FB);
    u16* pd        = (u16*)(w + OFF_PD);

    k_prep<<<B_ + 1, 256, 0, stream>>>(feats, labels, fb, sq, countsf, offs, perm,
                                       negcnt, S, possum, done);
    k_pairs<<<dim3(8, 8, 8), 512, 0, stream>>>(fb, sq, labels, S, pd);
    k_dap<<<NID, 64, 0, stream>>>(S, sq, countsf, offs, perm, dap);
    k_lossred<<<B_, 256, 0, stream>>>(pd, dap, labels, possum, negcnt, done, out);
}